// Round 6
// baseline (426.006 us; speedup 1.0000x reference)
//
#include <hip/hip_runtime.h>
#include <hip/hip_bf16.h>

// ============================================================================
// Head: K=x@Wk^T, Q=x@Wq^T, V=x@Wv^T, causal softmax(QK^T/8)@V
// B=4, T=4096, D=1024, H=64. fp32 I/O, bf16 MFMA compute.
//
// R6 changes (R5 attn: MfmaUtil 21%, ~3500 cyc/block-iter vs 850 MFMA floor;
// LDS port moved ~128KB/block-iter):
//  * V and K read DIRECTLY global->VGPR (frag-tiled b128 loads; qs-wave
//    duplication served by L1). Vlds dropped; LDS = P handoff only (2x5KB).
//    V(it+1) frags prefetched inside the PV MFMA loop (latency hidden).
//  * Block = 256 thr / 4 waves over 64 q-rows x 256 e-cols. S phase m-split:
//    wave w computes S rows [w*16,+16) x 32 s-cols (wave-local K loads).
//    PV phase: wave = (qs = w>>1) 32 q-rows x (es = w&1) 128 e-cols.
//  * 1024 blocks; qtile = g<32 ? 63-g : g-32 (complementary pairs, 66 iters);
//    (e0,b) -> fixed XCD under round-robin dispatch (V slice fits XCD L2).
//  * __launch_bounds__(256,3): ~12 waves/CU, 3 blocks co-resident.
// ============================================================================

typedef __attribute__((ext_vector_type(8))) short bf16x8;   // 8 bf16, 4 VGPRs
typedef __attribute__((ext_vector_type(4))) float f32x4;

typedef unsigned short u16;
typedef unsigned int u32;

__device__ inline u16 f2bf(float f) {
    u32 u = __builtin_bit_cast(u32, f);
    u = (u + 0x7fff + ((u >> 16) & 1)) >> 16;   // RNE
    return (u16)u;
}

__device__ inline void g2lds16(const void* g, void* l) {
    __builtin_amdgcn_global_load_lds(
        (const __attribute__((address_space(1))) unsigned int*)g,
        (__attribute__((address_space(3))) unsigned int*)l, 16, 0, 0);
}

// Fragment-tile addressing (16 rows x 32 k, 512 u16 = 1KB per tile):
//   element (r, k): u16 idx = ((r&15) + ((k>>3)&3)*16)*8 + (k&7)
// A-frag (m=lane&15, k=quad*8+j) and B-frag (n=lane&15, k=quad*8+j) reads are
// both "base + lane*16B" -> coalesced global / conflict-free LDS.

// ----------------------------------------------------------------------------
__global__ void cvt_x(const float* __restrict__ src, u16* __restrict__ dst,
                      int n) {
    const int i = (blockIdx.x * blockDim.x + threadIdx.x) * 4;
    if (i + 3 < n) {
        const float4 v = *(const float4*)(src + i);
        dst[i + 0] = f2bf(v.x);
        dst[i + 1] = f2bf(v.y);
        dst[i + 2] = f2bf(v.z);
        dst[i + 3] = f2bf(v.w);
    }
}

// Fused weight convert: Wk (1x), Wq (x 0.125*log2e), Wv (1x).
__global__ void cvt_w(const float* __restrict__ Wk, const float* __restrict__ Wq,
                      const float* __restrict__ Wv,
                      u16* __restrict__ Wkb, u16* __restrict__ Wqb,
                      u16* __restrict__ Wvb, float qscale) {
    const int i = (blockIdx.x * blockDim.x + threadIdx.x) * 4;
    const float* src; u16* dst; int j; float s = 1.0f;
    if (i < 65536)        { src = Wk; dst = Wkb; j = i; }
    else if (i < 131072)  { src = Wq; dst = Wqb; j = i - 65536; s = qscale; }
    else                  { src = Wv; dst = Wvb; j = i - 131072; }
    const float4 v = *(const float4*)(src + j);
    dst[j + 0] = f2bf(v.x * s);
    dst[j + 1] = f2bf(v.y * s);
    dst[j + 2] = f2bf(v.z * s);
    dst[j + 3] = f2bf(v.w * s);
}

// ----------------------------------------------------------------------------
// GEMM body: C = A[M][K] @ Bsel[N][K]^T, bf16, fp32 accum, 128x128, BK=64.
// lda = ldb = K = 1024. Outputs frag-tiled (MODE 1: Qf/Kf, MODE 2: Vf).
// ----------------------------------------------------------------------------
template <int MODE>
__device__ __forceinline__ void gemm_body(
    int m0, int n0,
    const u16* __restrict__ A,
    const u16* __restrict__ B0, const u16* __restrict__ B1, int nsplit,
    u16* __restrict__ D0, u16* __restrict__ D1,
    u16* Alds, u16* Blds)
{
    const int tid  = threadIdx.x;
    const int lane = tid & 63, w = tid >> 6;
    const int quad = lane >> 4, l15 = lane & 15;
    const int wr = w >> 1, wc = w & 1;
    const int mrow0 = wr * 64, ncol0 = wc * 64;

    f32x4 acc[4][4] = {};

    const int srow = (lane >> 3);
    const int scol = (lane & 7) * 8;

    for (int k0 = 0; k0 < 1024; k0 += 64) {
        __syncthreads();
#pragma unroll
        for (int c = 0; c < 4; ++c) {
            const int chunk = c * 4 + w;
            const int row = chunk * 8 + srow;
            const u16* ga = A + (size_t)(m0 + row) * 1024 + k0 + scol;
            g2lds16(ga, &Alds[chunk * 512]);
            const int brow = n0 + row;
            const u16* gb = (brow < nsplit ? B0 + (size_t)brow * 1024
                                           : B1 + (size_t)(brow - nsplit) * 1024)
                            + k0 + scol;
            g2lds16(gb, &Blds[chunk * 512]);
        }
        __syncthreads();

#pragma unroll
        for (int kk = 0; kk < 64; kk += 32) {
            bf16x8 af[4], bfr[4];
#pragma unroll
            for (int mb = 0; mb < 4; ++mb)
                af[mb] = *(const bf16x8*)&Alds[(mrow0 + mb * 16 + l15) * 64 + kk + quad * 8];
#pragma unroll
            for (int nb = 0; nb < 4; ++nb)
                bfr[nb] = *(const bf16x8*)&Blds[(ncol0 + nb * 16 + l15) * 64 + kk + quad * 8];
#pragma unroll
            for (int mb = 0; mb < 4; ++mb)
#pragma unroll
                for (int nb = 0; nb < 4; ++nb)
                    acc[mb][nb] = __builtin_amdgcn_mfma_f32_16x16x32_bf16(
                        af[mb], bfr[nb], acc[mb][nb], 0, 0, 0);
        }
    }

    // epilogue: C/D layout col=lane&15, row=quad*4+reg
#pragma unroll
    for (int mb = 0; mb < 4; ++mb)
#pragma unroll
        for (int nb = 0; nb < 4; ++nb)
#pragma unroll
            for (int r = 0; r < 4; ++r) {
                const int row = m0 + mrow0 + mb * 16 + quad * 4 + r;
                const int col = n0 + ncol0 + nb * 16 + l15;
                const u16 v = f2bf(acc[mb][nb][r]);
                if (MODE == 1) {
                    const int h = col & 63;
                    u16* dst = (col < 64) ? D0 : D1;
                    const size_t idx = (size_t)((row >> 4) * 2 + (h >> 5)) * 512
                                     + ((row & 15) + ((h >> 3) & 3) * 16) * 8
                                     + (h & 7);
                    dst[idx] = v;
                } else {
                    const size_t idx = (size_t)((row >> 4) * 512 + (col >> 5)) * 512
                                     + ((row & 15) + ((col >> 3) & 3) * 16) * 8
                                     + (col & 7);
                    D0[idx] = v;
                }
            }
}

// Combined GEMM dispatch: blocks [0,128) -> QK projection, [128,1152) -> Vt.
__global__ __launch_bounds__(256, 2) void gemm_all(
    const u16* __restrict__ xb,
    const u16* __restrict__ Wqb, const u16* __restrict__ Wkb,
    const u16* __restrict__ Wvb,
    u16* __restrict__ Qf, u16* __restrict__ Kf, u16* __restrict__ Vf)
{
    __shared__ u16 Alds[128 * 64];
    __shared__ u16 Blds[128 * 64];
    const int d = blockIdx.x;
    if (d < 128) {
        gemm_body<1>(d * 128, 0, xb, Wqb, Wkb, 64, Qf, Kf, Alds, Blds);
    } else {
        const int dd = d - 128;
        gemm_body<2>((dd >> 7) * 128, (dd & 127) * 128, Wvb, xb, xb, 1 << 30,
                     Vf, nullptr, Alds, Blds);
    }
}

// ----------------------------------------------------------------------------
// Flash attention, no-max softmax, V/K in registers, LDS = P handoff only.
// Block 256 thr / 4 waves: q-rows [qtile*64,+64), e-cols [e0,+256).
// S phase: wave w -> S rows [qtile*64+w*16,+16) x 32 s-cols.
// PV phase: wave w -> qs=w>>1 (32 q-rows), es=w&1 (128 e-cols).
// d in [0,1024): g=d>>4, qtile = g<32 ? 63-g : g-32, e0=((d>>2)&3)*256, b=d&3.
// ----------------------------------------------------------------------------
__global__ __launch_bounds__(256, 3) void attn_fa(
    const u16* __restrict__ Qf,
    const u16* __restrict__ Kf,
    const u16* __restrict__ Vf,
    float* __restrict__ Out)
{
    __shared__ u16 Plds[2][64 * 40];    // 2 x 5KB, row-pad 40

    const int tid  = threadIdx.x;
    const int lane = tid & 63, w = tid >> 6;
    const int quad = lane >> 4, l15 = lane & 15;

    const int d  = blockIdx.x;
    const int g  = d >> 4;
    const int qtile = (g < 32) ? (63 - g) : (g - 32);
    const int e0 = ((d >> 2) & 3) * 256;
    const int b  = d & 3;
    const int bt0 = b * 4096;

    const int qs = w >> 1, es = w & 1;
    const int qm0 = qtile * 64 + w * 16;      // this wave's S rows
    const int qp0 = qtile * 64 + qs * 32;     // this wave's PV rows

    // Q A-frags for S rows (1 mb x 2 kk), log2-domain scaled
    bf16x8 qf[2];
#pragma unroll
    for (int kk = 0; kk < 2; ++kk)
        qf[kk] = *(const bf16x8*)&Qf[(size_t)(((bt0 + qm0) >> 4) * 2 + kk) * 512 + lane * 8];

    const short o = (short)0x3F80;            // bf16 1.0
    const bf16x8 ones = {o, o, o, o, o, o, o, o};

    f32x4 acc[2][8] = {};                     // O accumulator [mb][nb]
    f32x4 accl[2] = {};                       // row sums
    bf16x8 vf[8];                             // persistent V frags (prefetch)

    const int ntiles = 2 * qtile + 2;
    const int slimS  = qm0 + 15;
    const int slimPV = qp0 + 31;

    const u16* Vbase = Vf + (size_t)((e0 >> 4) + es * 8) * 512 * 512 + lane * 8;

    auto loadK4 = [&](int jt, bf16x8* kf) {   // kf[nb*2+kk], full 32 s-cols
        const int bt = (bt0 + jt * 32) >> 4;
#pragma unroll
        for (int i = 0; i < 4; ++i) {
            const int nb = i >> 1, kk = i & 1;
            kf[i] = *(const bf16x8*)&Kf[(size_t)((bt + nb) * 2 + kk) * 512 + lane * 8];
        }
    };
    auto loadVfrag = [&](int jt, int nb) -> bf16x8 {
        const int stile = (bt0 + jt * 32) >> 5;
        return *(const bf16x8*)&Vbase[(size_t)(nb * 512 + stile) * 512];
    };
    auto computeP = [&](int jt, const bf16x8* kf) {
        const int s0 = jt * 32;
        f32x4 sf[2] = {};
#pragma unroll
        for (int nb = 0; nb < 2; ++nb)
#pragma unroll
            for (int kk = 0; kk < 2; ++kk)
                sf[nb] = __builtin_amdgcn_mfma_f32_16x16x32_bf16(
                    qf[kk], kf[nb * 2 + kk], sf[nb], 0, 0, 0);
        if (s0 + 31 > qm0) {                  // diagonal-crossing: mask
#pragma unroll
            for (int nb = 0; nb < 2; ++nb) {
                const int colabs = s0 + nb * 16 + l15;
#pragma unroll
                for (int r = 0; r < 4; ++r) {
                    const int rowabs = qm0 + quad * 4 + r;
                    sf[nb][r] = (colabs <= rowabs) ? sf[nb][r] : -__builtin_inff();
                }
            }
        }
        u16* Pl = &Plds[jt & 1][(w * 16 + quad * 4) * 40 + l15];
#pragma unroll
        for (int nb = 0; nb < 2; ++nb)
#pragma unroll
            for (int r = 0; r < 4; ++r)
                Pl[r * 40 + nb * 16] = f2bf(exp2f(sf[nb][r]));
    };

    // ---- prologue: tile 0 ----
#pragma unroll
    for (int nb = 0; nb < 8; ++nb) vf[nb] = loadVfrag(0, nb);
    {
        bf16x8 kf0[4];
        loadK4(0, kf0);
        computeP(0, kf0);
    }

    for (int it = 0; it < ntiles; ++it) {
        __syncthreads();                      // publishes P(it)
        const int buf = it & 1;
        const bool haveNext = (it + 1 < ntiles);
        const bool nextS  = haveNext && ((it + 1) * 32 <= slimS);
        const bool nextPV = haveNext && ((it + 1) * 32 <= slimPV);
        const bool curPV  = (it * 32 <= slimPV);

        bf16x8 kf[4];
        if (nextS) loadK4(it + 1, kf);        // latency hidden by PV MFMAs

        if (curPV) {
            bf16x8 pf[2];
#pragma unroll
            for (int mb = 0; mb < 2; ++mb)
                pf[mb] = *(const bf16x8*)&Plds[buf][(qs * 32 + mb * 16 + l15) * 40 + quad * 8];
#pragma unroll
            for (int mb = 0; mb < 2; ++mb)
                accl[mb] = __builtin_amdgcn_mfma_f32_16x16x32_bf16(
                    pf[mb], ones, accl[mb], 0, 0, 0);
#pragma unroll
            for (int nb = 0; nb < 8; ++nb) {
                const bf16x8 v = vf[nb];
                if (nextPV) vf[nb] = loadVfrag(it + 1, nb);  // prefetch
                acc[0][nb] = __builtin_amdgcn_mfma_f32_16x16x32_bf16(
                    pf[0], v, acc[0][nb], 0, 0, 0);
                acc[1][nb] = __builtin_amdgcn_mfma_f32_16x16x32_bf16(
                    pf[1], v, acc[1][nb], 0, 0, 0);
            }
        }

        if (nextS) computeP(it + 1, kf);
    }

    // ---- epilogue: normalize by row sums ----
    float rl[2][4];
#pragma unroll
    for (int mb = 0; mb < 2; ++mb)
#pragma unroll
        for (int r = 0; r < 4; ++r) rl[mb][r] = 1.0f / accl[mb][r];
#pragma unroll
    for (int mb = 0; mb < 2; ++mb)
#pragma unroll
        for (int nb = 0; nb < 8; ++nb)
#pragma unroll
            for (int r = 0; r < 4; ++r) {
                const int row = qp0 + mb * 16 + quad * 4 + r;
                const int col = e0 + es * 128 + nb * 16 + l15;
                Out[(size_t)(bt0 + row) * 1024 + col] = acc[mb][nb][r] * rl[mb][r];
            }
}

// ----------------------------------------------------------------------------
extern "C" void kernel_launch(void* const* d_in, const int* in_sizes, int n_in,
                              void* d_out, int out_size, void* d_ws, size_t ws_size,
                              hipStream_t stream) {
    const float* x  = (const float*)d_in[0];   // [4,4096,1024]
    const float* Wk = (const float*)d_in[1];   // [64,1024]
    const float* Wq = (const float*)d_in[2];   // [64,1024]
    const float* Wv = (const float*)d_in[3];   // [1024,1024]

    const int nx  = in_sizes[0];
    const int nwk = in_sizes[1];
    const int nwq = in_sizes[2];
    const int nwv = in_sizes[3];

    u16* xb  = (u16*)d_ws;
    u16* Wkb = xb  + (size_t)nx;
    u16* Wqb = Wkb + (size_t)nwk;
    u16* Wvb = Wqb + (size_t)nwq;
    u16* Qf  = Wvb + (size_t)nwv;                    // 1024 btiles * 2 * 512
    u16* Kf  = Qf  + (size_t)1024 * 2 * 512;
    u16* Vf  = Kf  + (size_t)1024 * 2 * 512;         // 64 etiles * 512 * 512
    float* out = (float*)d_out;

    const float qscale = 0.125f * 1.44269504088896f; // fold 1/sqrt(H)*log2(e)

    cvt_x<<<nx / 1024, 256, 0, stream>>>(x, xb, nx);
    cvt_w<<<(nwk + nwq + nwv) / 1024, 256, 0, stream>>>(Wk, Wq, Wv,
                                                        Wkb, Wqb, Wvb, qscale);

    gemm_all<<<1152, 256, 0, stream>>>(xb, Wqb, Wkb, Wvb, Qf, Kf, Vf);

    attn_fa<<<1024, 256, 0, stream>>>(Qf, Kf, Vf, out);
}